// Round 2
// baseline (288.334 us; speedup 1.0000x reference)
//
#include <hip/hip_runtime.h>
#include <math.h>

#define BB 4
#define NN 512
#define DD 64
#define EPS 1e-5f
#define NEG_SLOPE 0.01f
#define TI 8   // i-rows per block in attn_kernel
#define JC 8   // j-chunks (grid.y); j's per block = NN/JC = 64

typedef float f32x4 __attribute__((ext_vector_type(4)));

// Kernel A: per-row LayerNorm folded into the two projections.
// One wave (64 lanes) per row; lane d holds i_em[row, d].
__global__ void __launch_bounds__(256)
stats_kernel(const float* __restrict__ i_em,
             const float* __restrict__ W_a,
             const float* __restrict__ gamma,
             const float* __restrict__ beta,
             float* __restrict__ sq,
             float* __restrict__ sk) {
    int row  = (blockIdx.x * blockDim.x + threadIdx.x) >> 6;   // global wave id
    int lane = threadIdx.x & 63;
    if (row >= BB * NN) return;

    float x = i_em[row * DD + lane];

    float s = x;
    #pragma unroll
    for (int off = 32; off >= 1; off >>= 1) s += __shfl_xor(s, off, 64);
    float mu = s * (1.0f / DD);

    float dx = x - mu;
    float v = dx * dx;
    #pragma unroll
    for (int off = 32; off >= 1; off >>= 1) v += __shfl_xor(v, off, 64);
    float rstd = rsqrtf(v * (1.0f / DD) + EPS);

    float xn = dx * rstd * gamma[lane] + beta[lane];
    float pq = xn * W_a[lane];
    float pk = xn * W_a[DD + lane];
    #pragma unroll
    for (int off = 32; off >= 1; off >>= 1) {
        pq += __shfl_xor(pq, off, 64);
        pk += __shfl_xor(pk, off, 64);
    }
    if (lane == 0) { sq[row] = pq; sk[row] = pk; }
}

// Kernel B: grid (BB*NN/TI, JC). Block (ib, jc) owns rows i0..i0+7 and
// j-chunk [jc*64, jc*64+64).
// Softmax (rows i0..i0+7) runs only in jc==0 blocks: one wave per 2 rows,
// wave-local (no LDS, no barriers).
// Value phase: each xj load feeds TI=8 row-stores (load:store = 1:8);
// stores are non-temporal so the 256 MiB write-once stream doesn't evict
// the L2-resident i_em slice. 2048 blocks -> full wave occupancy.
__global__ void __launch_bounds__(256, 8)
attn_kernel(const float* __restrict__ i_em,
            const float* __restrict__ sq,
            const float* __restrict__ sk,
            const float* __restrict__ b_a,
            float* __restrict__ alphas,
            float* __restrict__ value) {
    const int ib   = blockIdx.x;       // 0 .. BB*NN/TI - 1
    const int jc   = blockIdx.y;       // 0 .. JC-1
    const int i0g  = ib * TI;          // global row base (b*NN + i0)
    const int b    = i0g >> 9;         // / NN
    const int t    = threadIdx.x;
    const int lane = t & 63;
    const int w    = t >> 6;           // wave id 0..3

    // ---- phase 1 (jc==0 blocks only): softmax over j, 2 rows per wave ----
    if (jc == 0) {
        const float bias = b_a[0];
        const float* skb = sk + b * NN;

        float sv[8];
        #pragma unroll
        for (int k = 0; k < 8; ++k) sv[k] = skb[lane + k * 64];

        #pragma unroll
        for (int rr = 0; rr < 2; ++rr) {
            const int row  = i0g + w + rr * 4;     // global row (b*NN + i)
            const float si = sq[row] + bias;

            float e[8];
            float m = -INFINITY;
            #pragma unroll
            for (int k = 0; k < 8; ++k) {
                float s = si + sv[k];
                s = (s >= 0.f) ? s : NEG_SLOPE * s;
                e[k] = s;
                m = fmaxf(m, s);
            }
            #pragma unroll
            for (int off = 32; off >= 1; off >>= 1) m = fmaxf(m, __shfl_xor(m, off, 64));

            float sum = 0.f;
            #pragma unroll
            for (int k = 0; k < 8; ++k) { e[k] = expf(e[k] - m); sum += e[k]; }
            #pragma unroll
            for (int off = 32; off >= 1; off >>= 1) sum += __shfl_xor(sum, off, 64);
            const float inv = 1.0f / sum;

            float* arow = alphas + (size_t)row * NN;
            #pragma unroll
            for (int k = 0; k < 8; ++k)
                __builtin_nontemporal_store(e[k] * inv, &arow[lane + k * 64]);
        }
    }

    // ---- phase 2: outer-product value writes for j-chunk ----
    const f32x4* em4 = (const f32x4*)i_em;
    const int d4 = t & 15;             // which float4 of D=64
    const int jg = t >> 4;             // j group 0..15
    const int j0 = jc * (NN / JC);     // chunk base
    const f32x4* emb = em4 + (size_t)b * NN * 16;

    f32x4 xi[TI];
    #pragma unroll
    for (int r = 0; r < TI; ++r) xi[r] = em4[(size_t)(i0g + r) * 16 + d4];

    f32x4* out0 = (f32x4*)value + (size_t)i0g * (NN * 16) + d4;

    #pragma unroll
    for (int k = 0; k < NN / JC / 16; ++k) {   // 4 iterations, fully unrolled
        const int j = j0 + jg + k * 16;
        const f32x4 xj = emb[j * 16 + d4];     // L2-hit; 1 load feeds TI stores
        #pragma unroll
        for (int r = 0; r < TI; ++r) {
            f32x4 o = xi[r] * xj;
            __builtin_nontemporal_store(o, out0 + (size_t)r * (NN * 16) + j * 16);
        }
    }
}

extern "C" void kernel_launch(void* const* d_in, const int* in_sizes, int n_in,
                              void* d_out, int out_size, void* d_ws, size_t ws_size,
                              hipStream_t stream) {
    const float* i_em  = (const float*)d_in[0];
    const float* W_a   = (const float*)d_in[1];
    const float* b_a   = (const float*)d_in[2];
    const float* gamma = (const float*)d_in[3];
    const float* beta  = (const float*)d_in[4];

    float* alphas = (float*)d_out;                        // B*N*N
    float* value  = (float*)d_out + (size_t)BB * NN * NN; // B*N*N*D

    float* sq = (float*)d_ws;          // B*N
    float* sk = sq + BB * NN;          // B*N

    // 2048 rows, 4 waves per 256-thread block -> 512 blocks
    stats_kernel<<<(BB * NN) / 4, 256, 0, stream>>>(i_em, W_a, gamma, beta, sq, sk);
    // (rows/TI) x JC = 256 x 8 = 2048 blocks
    dim3 grid((BB * NN) / TI, JC);
    attn_kernel<<<grid, 256, 0, stream>>>(i_em, sq, sk, b_a, alphas, value);
}

// Round 3
// 270.405 us; speedup vs baseline: 1.0663x; 1.0663x over previous
//
#include <hip/hip_runtime.h>
#include <math.h>

#define BB 4
#define NN 512
#define DD 64
#define EPS 1e-5f
#define NEG_SLOPE 0.01f
#define TI 8   // i-rows per block in attn_kernel
#define JC 8   // j-chunks (grid.y); j's per block = NN/JC = 64

typedef float f32x4 __attribute__((ext_vector_type(4)));

// Kernel A: per-row LayerNorm folded into the two projections.
// One wave (64 lanes) per row; lane d holds i_em[row, d].
__global__ void __launch_bounds__(256)
stats_kernel(const float* __restrict__ i_em,
             const float* __restrict__ W_a,
             const float* __restrict__ gamma,
             const float* __restrict__ beta,
             float* __restrict__ sq,
             float* __restrict__ sk) {
    int row  = (blockIdx.x * blockDim.x + threadIdx.x) >> 6;   // global wave id
    int lane = threadIdx.x & 63;
    if (row >= BB * NN) return;

    float x = i_em[row * DD + lane];

    float s = x;
    #pragma unroll
    for (int off = 32; off >= 1; off >>= 1) s += __shfl_xor(s, off, 64);
    float mu = s * (1.0f / DD);

    float dx = x - mu;
    float v = dx * dx;
    #pragma unroll
    for (int off = 32; off >= 1; off >>= 1) v += __shfl_xor(v, off, 64);
    float rstd = rsqrtf(v * (1.0f / DD) + EPS);

    float xn = dx * rstd * gamma[lane] + beta[lane];
    float pq = xn * W_a[lane];
    float pk = xn * W_a[DD + lane];
    #pragma unroll
    for (int off = 32; off >= 1; off >>= 1) {
        pq += __shfl_xor(pq, off, 64);
        pk += __shfl_xor(pk, off, 64);
    }
    if (lane == 0) { sq[row] = pq; sk[row] = pk; }
}

// Kernel B: grid (BB*NN/TI, JC). Block (ib, jc) owns rows i0..i0+7 and
// j-chunk [jc*64, jc*64+64).
// Softmax (rows i0..i0+7) runs only in jc==0 blocks: one wave per 2 rows,
// wave-local (no LDS, no barriers).
// Value phase: each xj load feeds TI=8 row-stores (load:store = 1:8).
// PLAIN stores (A/B vs round 1/2): nontemporal stores bypassed L2
// write-combining and regressed store BW — the fill kernel proves 6.4 TB/s
// goes through L2.
__global__ void __launch_bounds__(256, 8)
attn_kernel(const float* __restrict__ i_em,
            const float* __restrict__ sq,
            const float* __restrict__ sk,
            const float* __restrict__ b_a,
            float* __restrict__ alphas,
            float* __restrict__ value) {
    const int ib   = blockIdx.x;       // 0 .. BB*NN/TI - 1
    const int jc   = blockIdx.y;       // 0 .. JC-1
    const int i0g  = ib * TI;          // global row base (b*NN + i0)
    const int b    = i0g >> 9;         // / NN
    const int t    = threadIdx.x;
    const int lane = t & 63;
    const int w    = t >> 6;           // wave id 0..3

    // ---- phase 1 (jc==0 blocks only): softmax over j, 2 rows per wave ----
    if (jc == 0) {
        const float bias = b_a[0];
        const float* skb = sk + b * NN;

        float sv[8];
        #pragma unroll
        for (int k = 0; k < 8; ++k) sv[k] = skb[lane + k * 64];

        #pragma unroll
        for (int rr = 0; rr < 2; ++rr) {
            const int row  = i0g + w + rr * 4;     // global row (b*NN + i)
            const float si = sq[row] + bias;

            float e[8];
            float m = -INFINITY;
            #pragma unroll
            for (int k = 0; k < 8; ++k) {
                float s = si + sv[k];
                s = (s >= 0.f) ? s : NEG_SLOPE * s;
                e[k] = s;
                m = fmaxf(m, s);
            }
            #pragma unroll
            for (int off = 32; off >= 1; off >>= 1) m = fmaxf(m, __shfl_xor(m, off, 64));

            float sum = 0.f;
            #pragma unroll
            for (int k = 0; k < 8; ++k) { e[k] = expf(e[k] - m); sum += e[k]; }
            #pragma unroll
            for (int off = 32; off >= 1; off >>= 1) sum += __shfl_xor(sum, off, 64);
            const float inv = 1.0f / sum;

            float* arow = alphas + (size_t)row * NN;
            #pragma unroll
            for (int k = 0; k < 8; ++k)
                arow[lane + k * 64] = e[k] * inv;
        }
    }

    // ---- phase 2: outer-product value writes for j-chunk ----
    const f32x4* em4 = (const f32x4*)i_em;
    const int d4 = t & 15;             // which float4 of D=64
    const int jg = t >> 4;             // j group 0..15
    const int j0 = jc * (NN / JC);     // chunk base
    const f32x4* emb = em4 + (size_t)b * NN * 16;

    f32x4 xi[TI];
    #pragma unroll
    for (int r = 0; r < TI; ++r) xi[r] = em4[(size_t)(i0g + r) * 16 + d4];

    f32x4* out0 = (f32x4*)value + (size_t)i0g * (NN * 16) + d4;

    #pragma unroll
    for (int k = 0; k < NN / JC / 16; ++k) {   // 4 iterations, fully unrolled
        const int j = j0 + jg + k * 16;
        const f32x4 xj = emb[j * 16 + d4];     // L2-hit; 1 load feeds TI stores
        #pragma unroll
        for (int r = 0; r < TI; ++r) {
            f32x4 o = xi[r] * xj;
            out0[(size_t)r * (NN * 16) + j * 16] = o;
        }
    }
}

extern "C" void kernel_launch(void* const* d_in, const int* in_sizes, int n_in,
                              void* d_out, int out_size, void* d_ws, size_t ws_size,
                              hipStream_t stream) {
    const float* i_em  = (const float*)d_in[0];
    const float* W_a   = (const float*)d_in[1];
    const float* b_a   = (const float*)d_in[2];
    const float* gamma = (const float*)d_in[3];
    const float* beta  = (const float*)d_in[4];

    float* alphas = (float*)d_out;                        // B*N*N
    float* value  = (float*)d_out + (size_t)BB * NN * NN; // B*N*N*D

    float* sq = (float*)d_ws;          // B*N
    float* sk = sq + BB * NN;          // B*N

    // 2048 rows, 4 waves per 256-thread block -> 512 blocks
    stats_kernel<<<(BB * NN) / 4, 256, 0, stream>>>(i_em, W_a, gamma, beta, sq, sk);
    // (rows/TI) x JC = 256 x 8 = 2048 blocks
    dim3 grid((BB * NN) / TI, JC);
    attn_kernel<<<grid, 256, 0, stream>>>(i_em, sq, sk, b_a, alphas, value);
}